// Round 1
// baseline (258.344 us; speedup 1.0000x reference)
//
#include <hip/hip_runtime.h>
#include <hip/hip_bf16.h>
#include <cstdint>

#define B_ 2
#define S_ 2048
#define D_ 1024
#define H_ 16
#define HD_ 64
#define M_ (B_*S_)   // 4096

typedef unsigned short u16;
typedef __bf16 bf16x8 __attribute__((ext_vector_type(8)));
typedef u16 u16x8 __attribute__((ext_vector_type(8)));
typedef float f32x4 __attribute__((ext_vector_type(4)));

static __device__ __forceinline__ u16 f2bu(float f) {
  __bf16 b = (__bf16)f;
  return __builtin_bit_cast(unsigned short, b);
}

#define GLOAD16(g, l) __builtin_amdgcn_global_load_lds( \
    (__attribute__((address_space(1))) void*)(g), \
    (__attribute__((address_space(3))) void*)(l), 16, 0, 0)

// ---------------- LayerNorm: fp32 [4096][1024] -> bf16 h ----------------
__global__ __launch_bounds__(256) void ln_kernel(const float* __restrict__ x,
    const float* __restrict__ g, const float* __restrict__ be, u16* __restrict__ h) {
  const int row = blockIdx.x;
  const int t = threadIdx.x;
  float4 v = reinterpret_cast<const float4*>(x + (size_t)row * D_)[t];
  float s = v.x + v.y + v.z + v.w;
  float sq = v.x*v.x + v.y*v.y + v.z*v.z + v.w*v.w;
  #pragma unroll
  for (int off = 32; off >= 1; off >>= 1) {
    s  += __shfl_down(s, off);
    sq += __shfl_down(sq, off);
  }
  __shared__ float red[8];
  const int wave = t >> 6, lane = t & 63;
  if (lane == 0) { red[wave] = s; red[4 + wave] = sq; }
  __syncthreads();
  if (t == 0) {
    float ts = red[0]+red[1]+red[2]+red[3];
    float tq = red[4]+red[5]+red[6]+red[7];
    float mu = ts * (1.0f / D_);
    red[0] = mu;
    red[1] = rsqrtf(tq * (1.0f / D_) - mu*mu + 1e-5f);
  }
  __syncthreads();
  const float mu = red[0], rs = red[1];
  float4 gg = reinterpret_cast<const float4*>(g)[t];
  float4 bb = reinterpret_cast<const float4*>(be)[t];
  ushort4 o;
  o.x = f2bu((v.x - mu) * rs * gg.x + bb.x);
  o.y = f2bu((v.y - mu) * rs * gg.y + bb.y);
  o.z = f2bu((v.z - mu) * rs * gg.z + bb.z);
  o.w = f2bu((v.w - mu) * rs * gg.w + bb.w);
  reinterpret_cast<ushort4*>(h + (size_t)row * D_)[t] = o;
}

// ------------- Weight transpose+convert: W[k][n] fp32 -> Wt[n][k] bf16 -------------
__global__ __launch_bounds__(256) void wt_kernel(const float* __restrict__ W0,
    const float* __restrict__ W1, const float* __restrict__ W2, u16* __restrict__ wt) {
  const int z = blockIdx.z;
  const float* W = (z == 0) ? W0 : ((z == 1) ? W1 : W2);
  u16* out = wt + (size_t)z * D_ * D_;
  __shared__ float tile[32][33];
  const int n0 = blockIdx.x * 32, k0 = blockIdx.y * 32;
  const int tx = threadIdx.x, ty = threadIdx.y;
  #pragma unroll
  for (int j = 0; j < 4; ++j)
    tile[ty + 8*j][tx] = W[(size_t)(k0 + ty + 8*j) * D_ + n0 + tx];
  __syncthreads();
  #pragma unroll
  for (int j = 0; j < 4; ++j)
    out[(size_t)(n0 + ty + 8*j) * D_ + k0 + tx] = f2bu(tile[tx][ty + 8*j]);
}

// ------------- QKV GEMM: C[m][n] = h[m][k] * W[k][n], 128x128 tile, BK=32 -------------
// A = h bf16 [4096][1024]; B given as Wt[n][k] bf16. Output scattered to [B,H,S,HD] bf16.
__global__ __launch_bounds__(256) void qkv_gemm(const u16* __restrict__ hbuf,
    const u16* __restrict__ wt, u16* __restrict__ qkv) {
  const int z = blockIdx.z;
  const u16* Bt = wt + (size_t)z * D_ * D_;
  u16* outp = qkv + (size_t)z * (B_*H_*S_*HD_);
  __shared__ __align__(16) u16 As[128 * 32];
  __shared__ __align__(16) u16 Bs[128 * 32];
  const int t = threadIdx.x, lane = t & 63, wave = t >> 6;
  const int row0 = blockIdx.y * 128, col0 = blockIdx.x * 128;
  const int wm = wave >> 1, wn = wave & 1;
  f32x4 acc[4][4] = {};
  const u16* ag = hbuf + (size_t)(row0 + (t >> 2)) * D_ + (t & 3) * 8;
  const u16* bg = Bt   + (size_t)(col0 + (t >> 2)) * D_ + (t & 3) * 8;
  u16* lA = &As[wave * 512];
  u16* lB = &Bs[wave * 512];

  for (int k0 = 0; k0 < D_; k0 += 32) {
    GLOAD16(ag + k0,           lA);
    GLOAD16(ag + k0 + 64 * D_, lA + 2048);
    GLOAD16(bg + k0,           lB);
    GLOAD16(bg + k0 + 64 * D_, lB + 2048);
    __syncthreads();
    bf16x8 af[4], bfr[4];
    #pragma unroll
    for (int m = 0; m < 4; ++m)
      af[m] = *reinterpret_cast<const bf16x8*>(&As[(wm*64 + m*16 + (lane & 15)) * 32 + (lane >> 4) * 8]);
    #pragma unroll
    for (int n = 0; n < 4; ++n)
      bfr[n] = *reinterpret_cast<const bf16x8*>(&Bs[(wn*64 + n*16 + (lane & 15)) * 32 + (lane >> 4) * 8]);
    #pragma unroll
    for (int m = 0; m < 4; ++m) {
      #pragma unroll
      for (int n = 0; n < 4; ++n)
        acc[m][n] = __builtin_amdgcn_mfma_f32_16x16x32_bf16(af[m], bfr[n], acc[m][n], 0, 0, 0);
    }
    __syncthreads();
  }
  #pragma unroll
  for (int m = 0; m < 4; ++m) {
    #pragma unroll
    for (int n = 0; n < 4; ++n) {
      const int gcol = col0 + wn*64 + n*16 + (lane & 15);
      const int hI = gcol >> 6, dI = gcol & 63;
      #pragma unroll
      for (int r = 0; r < 4; ++r) {
        const int grow = row0 + wm*64 + m*16 + (lane >> 4) * 4 + r;
        const int bI = grow >> 11, sI = grow & (S_ - 1);
        outp[((size_t)(bI * H_ + hI) * S_ + sI) * HD_ + dI] = f2bu(acc[m][n][r]);
      }
    }
  }
}

// ------------- Flash attention: block = (qblock, head, batch), 4 waves x 16 q-rows -------------
__global__ __launch_bounds__(256) void attn_kernel(const u16* __restrict__ qkv,
    const float* __restrict__ mask, float* __restrict__ out) {
  const int qb = blockIdx.x, hI = blockIdx.y, bI = blockIdx.z;
  const size_t plane = (size_t)(bI * H_ + hI) * S_ * HD_;
  const u16* Qp = qkv + plane;
  const u16* Kp = qkv + (size_t)(B_*H_*S_*HD_) + plane;
  const u16* Vp = qkv + 2*(size_t)(B_*H_*S_*HD_) + plane;
  const int t = threadIdx.x, lane = t & 63, wave = t >> 6;
  const int q0 = qb * 64;
  __shared__ __align__(16) u16 Ks[32 * 72];   // [kv][d], rows padded 64->72 (bank spread)
  __shared__ __align__(16) u16 Vs[64 * 40];   // transposed [d][kv], rows padded 32->40
  __shared__ __align__(16) u16 Ps[4 * 16 * 40]; // per-wave P tile [16][40]

  bf16x8 qf[2];
  {
    const int qrow = q0 + wave * 16 + (lane & 15);
    #pragma unroll
    for (int kk = 0; kk < 2; ++kk)
      qf[kk] = *reinterpret_cast<const bf16x8*>(Qp + (size_t)qrow * HD_ + kk * 32 + (lane >> 4) * 8);
  }
  f32x4 acc_o[4] = {};
  float mrow[4], lrow[4];
  #pragma unroll
  for (int r = 0; r < 4; ++r) { mrow[r] = -1e30f; lrow[r] = 0.f; }

  const int sr = t >> 3, scc = (t & 7) * 8;  // staging: row (0..31), col-base

  for (int kv0 = 0; kv0 < S_; kv0 += 32) {
    __syncthreads();
    *reinterpret_cast<u16x8*>(&Ks[sr * 72 + scc]) =
        *reinterpret_cast<const u16x8*>(Kp + (size_t)(kv0 + sr) * HD_ + scc);
    u16x8 vv = *reinterpret_cast<const u16x8*>(Vp + (size_t)(kv0 + sr) * HD_ + scc);
    #pragma unroll
    for (int j = 0; j < 8; ++j) Vs[(scc + j) * 40 + sr] = vv[j];
    __syncthreads();

    // scores: S[q][kv] = sum_d Q[q][d] K[kv][d]
    f32x4 scf[2] = {};
    #pragma unroll
    for (int cf = 0; cf < 2; ++cf) {
      #pragma unroll
      for (int kk = 0; kk < 2; ++kk) {
        bf16x8 kf = *reinterpret_cast<const bf16x8*>(
            &Ks[(cf*16 + (lane & 15)) * 72 + kk*32 + (lane >> 4) * 8]);
        scf[cf] = __builtin_amdgcn_mfma_f32_16x16x32_bf16(qf[kk], kf, scf[cf], 0, 0, 0);
      }
    }
    float mv[2];
    #pragma unroll
    for (int cf = 0; cf < 2; ++cf)
      mv[cf] = mask[(size_t)bI * S_ + kv0 + cf*16 + (lane & 15)];

    float sf[4], p0[4], p1[4];
    #pragma unroll
    for (int r = 0; r < 4; ++r) {
      float a = scf[0][r] * 0.125f + mv[0];
      float b = scf[1][r] * 0.125f + mv[1];
      float tm = fmaxf(a, b);
      #pragma unroll
      for (int off = 1; off < 16; off <<= 1) tm = fmaxf(tm, __shfl_xor(tm, off));
      const float mnew = fmaxf(mrow[r], tm);
      sf[r] = __expf(mrow[r] - mnew);
      mrow[r] = mnew;
      p0[r] = __expf(a - mnew);
      p1[r] = __expf(b - mnew);
      float rs = p0[r] + p1[r];
      #pragma unroll
      for (int off = 1; off < 16; off <<= 1) rs += __shfl_xor(rs, off);
      lrow[r] = lrow[r] * sf[r] + rs;
    }
    // C-layout -> A-layout for P via per-wave LDS round-trip (bf16)
    u16* Pw = &Ps[wave * 16 * 40];
    #pragma unroll
    for (int r = 0; r < 4; ++r) {
      const int prow = (lane >> 4) * 4 + r;
      Pw[prow * 40 + (lane & 15)]      = f2bu(p0[r]);
      Pw[prow * 40 + 16 + (lane & 15)] = f2bu(p1[r]);
    }
    bf16x8 pf = *reinterpret_cast<const bf16x8*>(&Pw[(lane & 15) * 40 + (lane >> 4) * 8]);
    #pragma unroll
    for (int n = 0; n < 4; ++n) {
      #pragma unroll
      for (int r = 0; r < 4; ++r) acc_o[n][r] *= sf[r];
    }
    #pragma unroll
    for (int n = 0; n < 4; ++n) {
      bf16x8 vf = *reinterpret_cast<const bf16x8*>(&Vs[(n*16 + (lane & 15)) * 40 + (lane >> 4) * 8]);
      acc_o[n] = __builtin_amdgcn_mfma_f32_16x16x32_bf16(pf, vf, acc_o[n], 0, 0, 0);
    }
  }
  #pragma unroll
  for (int n = 0; n < 4; ++n) {
    const int d = n*16 + (lane & 15);
    #pragma unroll
    for (int r = 0; r < 4; ++r) {
      const int q = q0 + wave*16 + (lane >> 4)*4 + r;
      out[(size_t)(bI * S_ + q) * D_ + hI * HD_ + d] = acc_o[n][r] / lrow[r];
    }
  }
}

extern "C" void kernel_launch(void* const* d_in, const int* in_sizes, int n_in,
                              void* d_out, int out_size, void* d_ws, size_t ws_size,
                              hipStream_t stream) {
  const float* x     = (const float*)d_in[0];
  const float* mask  = (const float*)d_in[1];
  const float* gamma = (const float*)d_in[2];
  const float* beta  = (const float*)d_in[3];
  const float* Wq    = (const float*)d_in[4];
  const float* Wk    = (const float*)d_in[5];
  const float* Wv    = (const float*)d_in[6];
  float* out = (float*)d_out;

  char* ws = (char*)d_ws;
  u16* hbuf = (u16*)ws;                                        // 8 MiB: h bf16 [4096][1024]
  u16* wt   = (u16*)(ws + (size_t)M_*D_*2);                    // 6 MiB: Wt bf16 [3][1024][1024]
  u16* qkv  = (u16*)(ws + (size_t)M_*D_*2 + 3ull*D_*D_*2);     // 24 MiB: [3][B][H][S][HD] bf16

  hipLaunchKernelGGL(ln_kernel, dim3(M_), dim3(256), 0, stream, x, gamma, beta, hbuf);
  hipLaunchKernelGGL(wt_kernel, dim3(32, 32, 3), dim3(32, 8), 0, stream, Wq, Wk, Wv, wt);
  hipLaunchKernelGGL(qkv_gemm, dim3(8, 32, 3), dim3(256), 0, stream, hbuf, wt, qkv);
  hipLaunchKernelGGL(attn_kernel, dim3(S_/64, H_, B_), dim3(256), 0, stream, qkv, mask, out);
}

// Round 2
// 113.601 us; speedup vs baseline: 2.2741x; 2.2741x over previous
//
#include <hip/hip_runtime.h>
#include <hip/hip_bf16.h>
#include <cstdint>

#define B_ 2
#define S_ 2048
#define D_ 1024
#define H_ 16
#define HD_ 64
#define M_ (B_*S_)   // 4096

#define LOG2E 1.4426950408889634f
#define C1_ (0.125f * LOG2E)   // 1/sqrt(64) * log2(e)

typedef unsigned short u16;
typedef __bf16 bf16x8 __attribute__((ext_vector_type(8)));
typedef u16 u16x8 __attribute__((ext_vector_type(8)));
typedef float f32x4 __attribute__((ext_vector_type(4)));
typedef float f32x16 __attribute__((ext_vector_type(16)));
typedef int i32x4 __attribute__((ext_vector_type(4)));

static __device__ __forceinline__ u16 f2bu(float f) {
  __bf16 b = (__bf16)f;
  return __builtin_bit_cast(unsigned short, b);
}

static __device__ __forceinline__ int cvtpk(float a, float b) {
  int r;
  asm("v_cvt_pk_bf16_f32 %0, %1, %2" : "=v"(r) : "v"(a), "v"(b));
  return r;
}
// After: x = {l<32: x[l], l>=32: y[l-32]}, y = {l<32: x[l+32], l>=32: y[l]}
static __device__ __forceinline__ void plswap(int &x, int &y) {
  asm("v_permlane32_swap_b32 %0, %1" : "+v"(x), "+v"(y));
}

#define GLOAD16(g, l) __builtin_amdgcn_global_load_lds( \
    (__attribute__((address_space(1))) void*)(g), \
    (__attribute__((address_space(3))) void*)(l), 16, 0, 0)

// ---------------- LayerNorm: fp32 [4096][1024] -> bf16 h ----------------
__global__ __launch_bounds__(256) void ln_kernel(const float* __restrict__ x,
    const float* __restrict__ g, const float* __restrict__ be, u16* __restrict__ h) {
  const int row = blockIdx.x;
  const int t = threadIdx.x;
  float4 v = reinterpret_cast<const float4*>(x + (size_t)row * D_)[t];
  float s = v.x + v.y + v.z + v.w;
  float sq = v.x*v.x + v.y*v.y + v.z*v.z + v.w*v.w;
  #pragma unroll
  for (int off = 32; off >= 1; off >>= 1) {
    s  += __shfl_down(s, off);
    sq += __shfl_down(sq, off);
  }
  __shared__ float red[8];
  const int wave = t >> 6, lane = t & 63;
  if (lane == 0) { red[wave] = s; red[4 + wave] = sq; }
  __syncthreads();
  if (t == 0) {
    float ts = red[0]+red[1]+red[2]+red[3];
    float tq = red[4]+red[5]+red[6]+red[7];
    float mu = ts * (1.0f / D_);
    red[0] = mu;
    red[1] = rsqrtf(tq * (1.0f / D_) - mu*mu + 1e-5f);
  }
  __syncthreads();
  const float mu = red[0], rs = red[1];
  float4 gg = reinterpret_cast<const float4*>(g)[t];
  float4 bb = reinterpret_cast<const float4*>(be)[t];
  ushort4 o;
  o.x = f2bu((v.x - mu) * rs * gg.x + bb.x);
  o.y = f2bu((v.y - mu) * rs * gg.y + bb.y);
  o.z = f2bu((v.z - mu) * rs * gg.z + bb.z);
  o.w = f2bu((v.w - mu) * rs * gg.w + bb.w);
  reinterpret_cast<ushort4*>(h + (size_t)row * D_)[t] = o;
}

// ------------- Weight transpose+convert: W[k][n] fp32 -> Wt[n][k] bf16 -------------
__global__ __launch_bounds__(256) void wt_kernel(const float* __restrict__ W0,
    const float* __restrict__ W1, const float* __restrict__ W2, u16* __restrict__ wt) {
  const int z = blockIdx.z;
  const float* W = (z == 0) ? W0 : ((z == 1) ? W1 : W2);
  u16* out = wt + (size_t)z * D_ * D_;
  __shared__ float tile[32][33];
  const int n0 = blockIdx.x * 32, k0 = blockIdx.y * 32;
  const int tx = threadIdx.x, ty = threadIdx.y;
  #pragma unroll
  for (int j = 0; j < 4; ++j)
    tile[ty + 8*j][tx] = W[(size_t)(k0 + ty + 8*j) * D_ + n0 + tx];
  __syncthreads();
  #pragma unroll
  for (int j = 0; j < 4; ++j)
    out[(size_t)(n0 + ty + 8*j) * D_ + k0 + tx] = f2bu(tile[tx][ty + 8*j]);
}

// ------------- QKV GEMM: C[m][n] = h[m][k] * W[k][n], 128x128 tile, BK=32 -------------
// Q,K scattered to [B,H,S,HD] bf16; V scattered TRANSPOSED to [B,H,HD,S] bf16.
__global__ __launch_bounds__(256) void qkv_gemm(const u16* __restrict__ hbuf,
    const u16* __restrict__ wt, u16* __restrict__ qkv) {
  const int z = blockIdx.z;
  const u16* Bt = wt + (size_t)z * D_ * D_;
  u16* outp = qkv + (size_t)z * (B_*H_*S_*HD_);
  __shared__ __align__(16) u16 As[128 * 32];
  __shared__ __align__(16) u16 Bs[128 * 32];
  const int t = threadIdx.x, lane = t & 63, wave = t >> 6;
  const int row0 = blockIdx.y * 128, col0 = blockIdx.x * 128;
  const int wm = wave >> 1, wn = wave & 1;
  f32x4 acc[4][4] = {};
  const u16* ag = hbuf + (size_t)(row0 + (t >> 2)) * D_ + (t & 3) * 8;
  const u16* bg = Bt   + (size_t)(col0 + (t >> 2)) * D_ + (t & 3) * 8;
  u16* lA = &As[wave * 512];
  u16* lB = &Bs[wave * 512];

  for (int k0 = 0; k0 < D_; k0 += 32) {
    GLOAD16(ag + k0,           lA);
    GLOAD16(ag + k0 + 64 * D_, lA + 2048);
    GLOAD16(bg + k0,           lB);
    GLOAD16(bg + k0 + 64 * D_, lB + 2048);
    __syncthreads();
    bf16x8 af[4], bfr[4];
    #pragma unroll
    for (int m = 0; m < 4; ++m)
      af[m] = *reinterpret_cast<const bf16x8*>(&As[(wm*64 + m*16 + (lane & 15)) * 32 + (lane >> 4) * 8]);
    #pragma unroll
    for (int n = 0; n < 4; ++n)
      bfr[n] = *reinterpret_cast<const bf16x8*>(&Bs[(wn*64 + n*16 + (lane & 15)) * 32 + (lane >> 4) * 8]);
    #pragma unroll
    for (int m = 0; m < 4; ++m) {
      #pragma unroll
      for (int n = 0; n < 4; ++n)
        acc[m][n] = __builtin_amdgcn_mfma_f32_16x16x32_bf16(af[m], bfr[n], acc[m][n], 0, 0, 0);
    }
    __syncthreads();
  }
  #pragma unroll
  for (int m = 0; m < 4; ++m) {
    #pragma unroll
    for (int n = 0; n < 4; ++n) {
      const int gcol = col0 + wn*64 + n*16 + (lane & 15);
      const int hI = gcol >> 6, dI = gcol & 63;
      #pragma unroll
      for (int r = 0; r < 4; ++r) {
        const int grow = row0 + wm*64 + m*16 + (lane >> 4) * 4 + r;
        const int bI = grow >> 11, sI = grow & (S_ - 1);
        size_t idx;
        if (z == 2) idx = ((size_t)(bI * H_ + hI) * HD_ + dI) * S_ + sI;   // V transposed
        else        idx = ((size_t)(bI * H_ + hI) * S_ + sI) * HD_ + dI;
        outp[idx] = f2bu(acc[m][n][r]);
      }
    }
  }
}

// ------------- Flash attention: 8 waves x 32 q, KVBLK=64, swapped-QK 32x32 MFMA -------------
__global__ __launch_bounds__(512) void attn_kernel(const u16* __restrict__ qkv,
    const float* __restrict__ mask, float* __restrict__ out) {
  const int bid = blockIdx.x;
  // XCD-bijective: 8 q-tiles of one (b,h) plane share bid&7 -> same XCD
  const int qt = (bid >> 3) & 7;
  const int pidx = (bid & 7) + ((bid >> 6) << 3);   // 0..31 = b*16+h
  const int hI = pidx & 15, bI = pidx >> 4;
  const size_t plane = (size_t)pidx * (S_ * HD_);
  const u16* Qp  = qkv + plane;
  const u16* Kp  = qkv + (size_t)(B_*H_*S_*HD_) + plane;
  const u16* Vtp = qkv + 2*(size_t)(B_*H_*S_*HD_) + plane;   // [d][s] within plane

  const int t = threadIdx.x, lane = t & 63, wave = t >> 6;
  const int cl = lane & 31, hf = lane >> 5;

  __shared__ __align__(16) u16 KsBuf[2][64 * 64];   // swizzled [kv][d]
  __shared__ __align__(16) u16 VsBuf[2][64 * 64];   // swizzled [d][kv]
  __shared__ float maskLds[S_];

  // stage mask once (pre-scaled by log2e)
  {
    float4 mv = reinterpret_cast<const float4*>(mask + (size_t)bI * S_)[t];
    float4 sm = {mv.x * LOG2E, mv.y * LOG2E, mv.z * LOG2E, mv.w * LOG2E};
    reinterpret_cast<float4*>(maskLds)[t] = sm;
  }

  // Q fragments in registers: lane holds Q[q0+cl][dstep*16 + hf*8 .. +7]
  const int q0 = qt * 256 + wave * 32;
  bf16x8 qf[4];
  #pragma unroll
  for (int dstep = 0; dstep < 4; ++dstep)
    qf[dstep] = *reinterpret_cast<const bf16x8*>(
        Qp + (size_t)(q0 + cl) * HD_ + dstep * 16 + hf * 8);

  // staging source (pre-swizzled so LDS content is XOR-swizzled, dest linear)
  const int sr = t >> 3;                 // row 0..63
  const int scb = (t & 7) * 16;          // col byte 0..112
  const int scol = (scb ^ ((sr & 7) << 4)) >> 1;   // element col
  const u16* kSrcBase = Kp  + (size_t)sr * HD_ + scol;
  const u16* vSrcBase = Vtp + (size_t)sr * S_  + scol;

  f32x16 oacc0 = {}, oacc1 = {};
  float m = -1e30f, lsum = 0.f;

  // prologue stage
  GLOAD16(kSrcBase, &KsBuf[0][wave * 512]);
  GLOAD16(vSrcBase, &VsBuf[0][wave * 512]);
  int cur = 0;

  for (int kv0 = 0; kv0 < S_; kv0 += 64) {
    __syncthreads();   // drains vmcnt: buf[cur] ready
    if (kv0 + 64 < S_) {
      GLOAD16(kSrcBase + (size_t)(kv0 + 64) * HD_, &KsBuf[cur ^ 1][wave * 512]);
      GLOAD16(vSrcBase + (kv0 + 64),               &VsBuf[cur ^ 1][wave * 512]);
    }
    const char* Ks = (const char*)KsBuf[cur];
    const char* Vs = (const char*)VsBuf[cur];

    #pragma unroll
    for (int sub = 0; sub < 2; ++sub) {
      // ---- QK^T (swapped): S^T[kv][q], lane: col q = cl, 16 kv regs ----
      f32x16 sacc = {};
      const int krow = sub * 32 + cl;
      const int kswz = (krow & 7) << 4;
      #pragma unroll
      for (int dstep = 0; dstep < 4; ++dstep) {
        bf16x8 kf = *reinterpret_cast<const bf16x8*>(
            Ks + krow * 128 + ((dstep * 32 + hf * 16) ^ kswz));
        sacc = __builtin_amdgcn_mfma_f32_32x32x16_bf16(kf, qf[dstep], sacc, 0, 0, 0);
      }
      // ---- softmax (exp2 domain); kv_local(reg) = (reg&3)+8*(reg>>2)+4*hf ----
      const int kvb = kv0 + sub * 32;
      float4 m0 = *reinterpret_cast<const float4*>(&maskLds[kvb + 4 * hf]);
      float4 m1 = *reinterpret_cast<const float4*>(&maskLds[kvb + 8 + 4 * hf]);
      float4 m2 = *reinterpret_cast<const float4*>(&maskLds[kvb + 16 + 4 * hf]);
      float4 m3 = *reinterpret_cast<const float4*>(&maskLds[kvb + 24 + 4 * hf]);
      float z[16];
      #pragma unroll
      for (int r = 0; r < 4; ++r) {
        z[r]      = sacc[r]      * C1_ + ((const float*)&m0)[r];
        z[r + 4]  = sacc[r + 4]  * C1_ + ((const float*)&m1)[r];
        z[r + 8]  = sacc[r + 8]  * C1_ + ((const float*)&m2)[r];
        z[r + 12] = sacc[r + 12] * C1_ + ((const float*)&m3)[r];
      }
      float tm = z[0];
      #pragma unroll
      for (int r = 1; r < 16; ++r) tm = fmaxf(tm, z[r]);
      tm = fmaxf(tm, __shfl_xor(tm, 32));
      const float mnew = fmaxf(m, tm);
      const float sf = __builtin_amdgcn_exp2f(m - mnew);
      m = mnew;
      float p[16]; float rs = 0.f;
      #pragma unroll
      for (int r = 0; r < 16; ++r) { p[r] = __builtin_amdgcn_exp2f(z[r] - mnew); rs += p[r]; }
      rs += __shfl_xor(rs, 32);
      lsum = lsum * sf + rs;
      oacc0 = oacc0 * sf;
      oacc1 = oacc1 * sf;
      // ---- pack P -> PV B-fragments (cvt_pk + permlane32_swap) ----
      int pk01 = cvtpk(p[0], p[1]),  pk23 = cvtpk(p[2], p[3]);
      int pk45 = cvtpk(p[4], p[5]),  pk67 = cvtpk(p[6], p[7]);
      int pk89 = cvtpk(p[8], p[9]),  pkAB = cvtpk(p[10], p[11]);
      int pkCD = cvtpk(p[12], p[13]), pkEF = cvtpk(p[14], p[15]);
      plswap(pk01, pk45);   // -> chunk0 u0, u2
      plswap(pk23, pk67);   // -> chunk0 u1, u3
      plswap(pk89, pkCD);   // -> chunk1 u0, u2
      plswap(pkAB, pkEF);   // -> chunk1 u1, u3
      i32x4 c0 = {pk01, pk23, pk45, pk67};
      i32x4 c1 = {pk89, pkAB, pkCD, pkEF};
      bf16x8 pf0 = __builtin_bit_cast(bf16x8, c0);
      bf16x8 pf1 = __builtin_bit_cast(bf16x8, c1);
      // ---- PV: O^T[d][q] += V^T[d][kv16] * P^T[kv16][q] ----
      const int vrow0 = cl, vrow1 = 32 + cl;
      const int vswz0 = (vrow0 & 7) << 4, vswz1 = (vrow1 & 7) << 4;
      const int kb0 = (sub * 32 + hf * 8) * 2;        // chunk 0 kv byte
      const int kb1 = (sub * 32 + 16 + hf * 8) * 2;   // chunk 1 kv byte
      bf16x8 vf;
      vf = *reinterpret_cast<const bf16x8*>(Vs + vrow0 * 128 + (kb0 ^ vswz0));
      oacc0 = __builtin_amdgcn_mfma_f32_32x32x16_bf16(vf, pf0, oacc0, 0, 0, 0);
      vf = *reinterpret_cast<const bf16x8*>(Vs + vrow1 * 128 + (kb0 ^ vswz1));
      oacc1 = __builtin_amdgcn_mfma_f32_32x32x16_bf16(vf, pf0, oacc1, 0, 0, 0);
      vf = *reinterpret_cast<const bf16x8*>(Vs + vrow0 * 128 + (kb1 ^ vswz0));
      oacc0 = __builtin_amdgcn_mfma_f32_32x32x16_bf16(vf, pf1, oacc0, 0, 0, 0);
      vf = *reinterpret_cast<const bf16x8*>(Vs + vrow1 * 128 + (kb1 ^ vswz1));
      oacc1 = __builtin_amdgcn_mfma_f32_32x32x16_bf16(vf, pf1, oacc1, 0, 0, 0);
    }
    cur ^= 1;
  }

  // ---- epilogue: O[q][d] = oacc / lsum; d = dsub*32 + (reg&3) + 8*(reg>>2) + 4*hf ----
  const float rinv = 1.0f / lsum;
  float* orow = out + ((size_t)bI * S_ + q0 + cl) * D_ + hI * HD_;
  #pragma unroll
  for (int j = 0; j < 4; ++j) {
    float4 o0 = {oacc0[4*j] * rinv, oacc0[4*j+1] * rinv, oacc0[4*j+2] * rinv, oacc0[4*j+3] * rinv};
    float4 o1 = {oacc1[4*j] * rinv, oacc1[4*j+1] * rinv, oacc1[4*j+2] * rinv, oacc1[4*j+3] * rinv};
    *reinterpret_cast<float4*>(orow + 8*j + 4*hf)      = o0;
    *reinterpret_cast<float4*>(orow + 32 + 8*j + 4*hf) = o1;
  }
}

extern "C" void kernel_launch(void* const* d_in, const int* in_sizes, int n_in,
                              void* d_out, int out_size, void* d_ws, size_t ws_size,
                              hipStream_t stream) {
  const float* x     = (const float*)d_in[0];
  const float* mask  = (const float*)d_in[1];
  const float* gamma = (const float*)d_in[2];
  const float* beta  = (const float*)d_in[3];
  const float* Wq    = (const float*)d_in[4];
  const float* Wk    = (const float*)d_in[5];
  const float* Wv    = (const float*)d_in[6];
  float* out = (float*)d_out;

  char* ws = (char*)d_ws;
  u16* hbuf = (u16*)ws;                                        // 8 MiB
  u16* wt   = (u16*)(ws + (size_t)M_*D_*2);                    // 6 MiB
  u16* qkv  = (u16*)(ws + (size_t)M_*D_*2 + 3ull*D_*D_*2);     // 24 MiB

  hipLaunchKernelGGL(ln_kernel, dim3(M_), dim3(256), 0, stream, x, gamma, beta, hbuf);
  hipLaunchKernelGGL(wt_kernel, dim3(32, 32, 3), dim3(32, 8), 0, stream, Wq, Wk, Wv, wt);
  hipLaunchKernelGGL(qkv_gemm, dim3(8, 32, 3), dim3(256), 0, stream, hbuf, wt, qkv);
  hipLaunchKernelGGL(attn_kernel, dim3(256), dim3(512), 0, stream, qkv, mask, out);
}

// Round 3
// 110.960 us; speedup vs baseline: 2.3283x; 1.0238x over previous
//
#include <hip/hip_runtime.h>
#include <hip/hip_bf16.h>
#include <cstdint>

#define B_ 2
#define S_ 2048
#define D_ 1024
#define H_ 16
#define HD_ 64
#define M_ (B_*S_)   // 4096

#define LOG2E 1.4426950408889634f
#define C1_ (0.125f * LOG2E)   // 1/sqrt(64) * log2(e)

typedef unsigned short u16;
typedef __bf16 bf16x8 __attribute__((ext_vector_type(8)));
typedef u16 u16x8 __attribute__((ext_vector_type(8)));
typedef float f32x4 __attribute__((ext_vector_type(4)));
typedef float f32x16 __attribute__((ext_vector_type(16)));
typedef int i32x4 __attribute__((ext_vector_type(4)));

static __device__ __forceinline__ u16 f2bu(float f) {
  __bf16 b = (__bf16)f;
  return __builtin_bit_cast(unsigned short, b);
}

static __device__ __forceinline__ int cvtpk(float a, float b) {
  int r;
  asm("v_cvt_pk_bf16_f32 %0, %1, %2" : "=v"(r) : "v"(a), "v"(b));
  return r;
}
static __device__ __forceinline__ void plswap(int &x, int &y) {
  asm("v_permlane32_swap_b32 %0, %1" : "+v"(x), "+v"(y));
}

#define GLOAD16(g, l) __builtin_amdgcn_global_load_lds( \
    (__attribute__((address_space(1))) void*)(g), \
    (__attribute__((address_space(3))) void*)(l), 16, 0, 0)

// ---------------- LayerNorm: fp32 [4096][1024] -> bf16 h ----------------
__global__ __launch_bounds__(256) void ln_kernel(const float* __restrict__ x,
    const float* __restrict__ g, const float* __restrict__ be, u16* __restrict__ h) {
  const int row = blockIdx.x;
  const int t = threadIdx.x;
  float4 v = reinterpret_cast<const float4*>(x + (size_t)row * D_)[t];
  float s = v.x + v.y + v.z + v.w;
  float sq = v.x*v.x + v.y*v.y + v.z*v.z + v.w*v.w;
  #pragma unroll
  for (int off = 32; off >= 1; off >>= 1) {
    s  += __shfl_down(s, off);
    sq += __shfl_down(sq, off);
  }
  __shared__ float red[8];
  const int wave = t >> 6, lane = t & 63;
  if (lane == 0) { red[wave] = s; red[4 + wave] = sq; }
  __syncthreads();
  if (t == 0) {
    float ts = red[0]+red[1]+red[2]+red[3];
    float tq = red[4]+red[5]+red[6]+red[7];
    float mu = ts * (1.0f / D_);
    red[0] = mu;
    red[1] = rsqrtf(tq * (1.0f / D_) - mu*mu + 1e-5f);
  }
  __syncthreads();
  const float mu = red[0], rs = red[1];
  float4 gg = reinterpret_cast<const float4*>(g)[t];
  float4 bb = reinterpret_cast<const float4*>(be)[t];
  ushort4 o;
  o.x = f2bu((v.x - mu) * rs * gg.x + bb.x);
  o.y = f2bu((v.y - mu) * rs * gg.y + bb.y);
  o.z = f2bu((v.z - mu) * rs * gg.z + bb.z);
  o.w = f2bu((v.w - mu) * rs * gg.w + bb.w);
  reinterpret_cast<ushort4*>(h + (size_t)row * D_)[t] = o;
}

// ------------- Weight transpose+convert: W[k][n] fp32 -> Wt[n][k] bf16 -------------
__global__ __launch_bounds__(256) void wt_kernel(const float* __restrict__ W0,
    const float* __restrict__ W1, const float* __restrict__ W2, u16* __restrict__ wt) {
  const int z = blockIdx.z;
  const float* W = (z == 0) ? W0 : ((z == 1) ? W1 : W2);
  u16* out = wt + (size_t)z * D_ * D_;
  __shared__ float tile[32][33];
  const int n0 = blockIdx.x * 32, k0 = blockIdx.y * 32;
  const int tx = threadIdx.x, ty = threadIdx.y;
  #pragma unroll
  for (int j = 0; j < 4; ++j)
    tile[ty + 8*j][tx] = W[(size_t)(k0 + ty + 8*j) * D_ + n0 + tx];
  __syncthreads();
  #pragma unroll
  for (int j = 0; j < 4; ++j)
    out[(size_t)(n0 + ty + 8*j) * D_ + k0 + tx] = f2bu(tile[tx][ty + 8*j]);
}

// ------------- QKV GEMM: 128x128 tile, BK=32, T2-swizzled LDS -------------
// Q,K scattered to [B,H,S,HD] bf16; V scattered TRANSPOSED to [B,H,HD,S] bf16.
__global__ __launch_bounds__(256) void qkv_gemm(const u16* __restrict__ hbuf,
    const u16* __restrict__ wt, u16* __restrict__ qkv) {
  const int z = blockIdx.z;
  const u16* Bt = wt + (size_t)z * D_ * D_;
  u16* outp = qkv + (size_t)z * (B_*H_*S_*HD_);
  __shared__ __align__(16) u16 As[128 * 32];
  __shared__ __align__(16) u16 Bs[128 * 32];
  const int t = threadIdx.x, lane = t & 63, wave = t >> 6;
  const int row0 = blockIdx.y * 128, col0 = blockIdx.x * 128;
  const int wm = wave >> 1, wn = wave & 1;
  f32x4 acc[4][4] = {};
  // pre-swizzled source: LDS[row][chunk j] = global chunk j ^ ((row>>1)&3)
  const int schunk = (t & 3) ^ ((t >> 3) & 3);
  const u16* ag = hbuf + (size_t)(row0 + (t >> 2)) * D_ + schunk * 8;
  const u16* bg = Bt   + (size_t)(col0 + (t >> 2)) * D_ + schunk * 8;
  u16* lA = &As[wave * 512];
  u16* lB = &Bs[wave * 512];
  const char* Ac = (const char*)As;
  const char* Bc = (const char*)Bs;
  const int cbase = (((lane >> 4) ^ ((lane >> 1) & 3)) << 4);

  for (int k0 = 0; k0 < D_; k0 += 32) {
    GLOAD16(ag + k0,           lA);
    GLOAD16(ag + k0 + 64 * D_, lA + 2048);
    GLOAD16(bg + k0,           lB);
    GLOAD16(bg + k0 + 64 * D_, lB + 2048);
    __syncthreads();
    bf16x8 af[4], bfr[4];
    #pragma unroll
    for (int m = 0; m < 4; ++m)
      af[m] = *reinterpret_cast<const bf16x8*>(Ac + (wm*64 + m*16 + (lane & 15)) * 64 + cbase);
    #pragma unroll
    for (int n = 0; n < 4; ++n)
      bfr[n] = *reinterpret_cast<const bf16x8*>(Bc + (wn*64 + n*16 + (lane & 15)) * 64 + cbase);
    #pragma unroll
    for (int m = 0; m < 4; ++m) {
      #pragma unroll
      for (int n = 0; n < 4; ++n)
        acc[m][n] = __builtin_amdgcn_mfma_f32_16x16x32_bf16(af[m], bfr[n], acc[m][n], 0, 0, 0);
    }
    __syncthreads();
  }
  #pragma unroll
  for (int m = 0; m < 4; ++m) {
    #pragma unroll
    for (int n = 0; n < 4; ++n) {
      const int gcol = col0 + wn*64 + n*16 + (lane & 15);
      const int hI = gcol >> 6, dI = gcol & 63;
      #pragma unroll
      for (int r = 0; r < 4; ++r) {
        const int grow = row0 + wm*64 + m*16 + (lane >> 4) * 4 + r;
        const int bI = grow >> 11, sI = grow & (S_ - 1);
        size_t idx;
        if (z == 2) idx = ((size_t)(bI * H_ + hI) * HD_ + dI) * S_ + sI;   // V transposed
        else        idx = ((size_t)(bI * H_ + hI) * S_ + sI) * HD_ + dI;
        outp[idx] = f2bu(acc[m][n][r]);
      }
    }
  }
}

// ---- softmax + pack (defer-max, offset -8 baked into staged mask) ----
static __device__ __forceinline__ void sm_pack(
    const f32x16& s, const float* __restrict__ mrow, int hf,
    float& dm, float& lsum, f32x16& o0, f32x16& o1,
    bf16x8& pfA, bf16x8& pfB) {
  float4 m0 = *reinterpret_cast<const float4*>(mrow + 4*hf);
  float4 m1 = *reinterpret_cast<const float4*>(mrow + 8 + 4*hf);
  float4 m2 = *reinterpret_cast<const float4*>(mrow + 16 + 4*hf);
  float4 m3 = *reinterpret_cast<const float4*>(mrow + 24 + 4*hf);
  float zb[16];
  #pragma unroll
  for (int r = 0; r < 4; ++r) {
    zb[r]      = s[r]      * C1_ + ((const float*)&m0)[r];
    zb[r + 4]  = s[r + 4]  * C1_ + ((const float*)&m1)[r];
    zb[r + 8]  = s[r + 8]  * C1_ + ((const float*)&m2)[r];
    zb[r + 12] = s[r + 12] * C1_ + ((const float*)&m3)[r];
  }
  // guard-max tree (v_max3-fusable, depth 3)
  float a0 = fmaxf(fmaxf(zb[0], zb[1]), zb[2]);
  float a1 = fmaxf(fmaxf(zb[3], zb[4]), zb[5]);
  float a2 = fmaxf(fmaxf(zb[6], zb[7]), zb[8]);
  float a3 = fmaxf(fmaxf(zb[9], zb[10]), zb[11]);
  float a4 = fmaxf(fmaxf(zb[12], zb[13]), zb[14]);
  float tm = fmaxf(fmaxf(fmaxf(a0, a1), fmaxf(a2, a3)), fmaxf(a4, zb[15]));
  tm = fmaxf(tm, __shfl_xor(tm, 32));
  if (__builtin_expect(__any(tm > dm + 8.0f), 0)) {   // safety rescale (cold)
    float dnew = fmaxf(dm, tm - 8.0f);
    float sf = __builtin_amdgcn_exp2f(dm - dnew);
    lsum *= sf; o0 = o0 * sf; o1 = o1 * sf; dm = dnew;
  }
  float p[16];
  #pragma unroll
  for (int r = 0; r < 16; ++r) p[r] = __builtin_amdgcn_exp2f(zb[r] - dm);
  float s01 = (p[0] + p[1]) + (p[2] + p[3]);
  float s23 = (p[4] + p[5]) + (p[6] + p[7]);
  float s45 = (p[8] + p[9]) + (p[10] + p[11]);
  float s67 = (p[12] + p[13]) + (p[14] + p[15]);
  float rs = (s01 + s23) + (s45 + s67);
  rs += __shfl_xor(rs, 32);
  lsum += rs;
  int pk01 = cvtpk(p[0], p[1]),   pk23 = cvtpk(p[2], p[3]);
  int pk45 = cvtpk(p[4], p[5]),   pk67 = cvtpk(p[6], p[7]);
  int pk89 = cvtpk(p[8], p[9]),   pkAB = cvtpk(p[10], p[11]);
  int pkCD = cvtpk(p[12], p[13]), pkEF = cvtpk(p[14], p[15]);
  plswap(pk01, pk45); plswap(pk23, pk67);
  plswap(pk89, pkCD); plswap(pkAB, pkEF);
  i32x4 c0 = {pk01, pk23, pk45, pk67};
  i32x4 c1 = {pk89, pkAB, pkCD, pkEF};
  pfA = __builtin_bit_cast(bf16x8, c0);
  pfB = __builtin_bit_cast(bf16x8, c1);
}

// ------------- Flash attention: 4 waves x 32 q, KVBLK=64, 2-sub pipeline -------------
__global__ __launch_bounds__(256, 2) void attn_kernel(const u16* __restrict__ qkv,
    const float* __restrict__ mask, float* __restrict__ out) {
  const int bid = blockIdx.x;
  // bijective XCD map: all 16 q-tiles of plane p land on XCD (p&7)
  const int x = bid & 7, rr = bid >> 3;
  const int j = rr & 15;                    // q-tile (128 q)
  const int pidx = x + ((rr >> 4) << 3);    // plane 0..31 = b*16+h
  const int hI = pidx & 15, bI = pidx >> 4;
  const size_t plane = (size_t)pidx * (S_ * HD_);
  const u16* Qp  = qkv + plane;
  const u16* Kp  = qkv + (size_t)(B_*H_*S_*HD_) + plane;
  const u16* Vtp = qkv + 2*(size_t)(B_*H_*S_*HD_) + plane;   // [d][s]

  const int t = threadIdx.x, lane = t & 63, wave = t >> 6;
  const int cl = lane & 31, hf = lane >> 5;
  const int swz = (cl & 7) << 4;   // shared by rows cl and 32+cl

  __shared__ __align__(16) u16 KsBuf[2][64 * 64];
  __shared__ __align__(16) u16 VsBuf[2][64 * 64];
  __shared__ float maskLds[S_];

  // stage mask once: mask*log2e - 8 (defer-max offset baked in)
  #pragma unroll
  for (int i = 0; i < 2; ++i) {
    float4 mv = reinterpret_cast<const float4*>(mask + (size_t)bI * S_)[t + i*256];
    float4 sm = {mv.x * LOG2E - 8.0f, mv.y * LOG2E - 8.0f,
                 mv.z * LOG2E - 8.0f, mv.w * LOG2E - 8.0f};
    reinterpret_cast<float4*>(maskLds)[t + i*256] = sm;
  }

  const int q0 = j * 128 + wave * 32;
  bf16x8 qf[4];
  #pragma unroll
  for (int d = 0; d < 4; ++d)
    qf[d] = *reinterpret_cast<const bf16x8*>(
        Qp + (size_t)(q0 + cl) * HD_ + d * 16 + hf * 8);

  // staging: pre-swizzled source, linear LDS dest
  const int sr = t >> 3;                               // row 0..31 (round0)
  const int scol = (((t & 7) * 16) ^ ((sr & 7) << 4)) >> 1;
  const u16* kSrc = Kp  + (size_t)sr * HD_ + scol;
  const u16* vSrc = Vtp + (size_t)sr * S_  + scol;
  const int L0 = wave * 512, L1 = 2048 + wave * 512;

  f32x16 oacc0 = {}, oacc1 = {};
  float dm = 0.f, lsum = 0.f;

  GLOAD16(kSrc,                  &KsBuf[0][L0]);
  GLOAD16(kSrc + 32 * HD_,       &KsBuf[0][L1]);
  GLOAD16(vSrc,                  &VsBuf[0][L0]);
  GLOAD16(vSrc + 32 * (size_t)S_, &VsBuf[0][L1]);
  int cur = 0;

  for (int kv0 = 0; kv0 < S_; kv0 += 64) {
    __syncthreads();   // buf[cur] ready (drains vmcnt)
    if (kv0 + 64 < S_) {
      const u16* kn = kSrc + (size_t)(kv0 + 64) * HD_;
      const u16* vn = vSrc + (kv0 + 64);
      GLOAD16(kn,                   &KsBuf[cur ^ 1][L0]);
      GLOAD16(kn + 32 * HD_,        &KsBuf[cur ^ 1][L1]);
      GLOAD16(vn,                   &VsBuf[cur ^ 1][L0]);
      GLOAD16(vn + 32 * (size_t)S_, &VsBuf[cur ^ 1][L1]);
    }
    const char* Ks = (const char*)KsBuf[cur];
    const char* Vs = (const char*)VsBuf[cur];

    // ---- QK^T both subs up-front (8 independent MFMAs) ----
    f32x16 s0 = {}, s1 = {};
    __builtin_amdgcn_s_setprio(1);
    #pragma unroll
    for (int d = 0; d < 4; ++d) {
      bf16x8 kf = *reinterpret_cast<const bf16x8*>(
          Ks + cl * 128 + ((d * 32 + hf * 16) ^ swz));
      s0 = __builtin_amdgcn_mfma_f32_32x32x16_bf16(kf, qf[d], s0, 0, 0, 0);
    }
    #pragma unroll
    for (int d = 0; d < 4; ++d) {
      bf16x8 kf = *reinterpret_cast<const bf16x8*>(
          Ks + (32 + cl) * 128 + ((d * 32 + hf * 16) ^ swz));
      s1 = __builtin_amdgcn_mfma_f32_32x32x16_bf16(kf, qf[d], s1, 0, 0, 0);
    }
    __builtin_amdgcn_s_setprio(0);

    bf16x8 pA, pB;
    // ---- SM0 (overlaps QK1 drain) + PV0 ----
    sm_pack(s0, maskLds + kv0, hf, dm, lsum, oacc0, oacc1, pA, pB);
    __builtin_amdgcn_s_setprio(1);
    {
      bf16x8 vf;
      vf = *reinterpret_cast<const bf16x8*>(Vs + cl * 128 + ((hf * 16) ^ swz));
      oacc0 = __builtin_amdgcn_mfma_f32_32x32x16_bf16(vf, pA, oacc0, 0, 0, 0);
      vf = *reinterpret_cast<const bf16x8*>(Vs + (32 + cl) * 128 + ((hf * 16) ^ swz));
      oacc1 = __builtin_amdgcn_mfma_f32_32x32x16_bf16(vf, pA, oacc1, 0, 0, 0);
      vf = *reinterpret_cast<const bf16x8*>(Vs + cl * 128 + ((32 + hf * 16) ^ swz));
      oacc0 = __builtin_amdgcn_mfma_f32_32x32x16_bf16(vf, pB, oacc0, 0, 0, 0);
      vf = *reinterpret_cast<const bf16x8*>(Vs + (32 + cl) * 128 + ((32 + hf * 16) ^ swz));
      oacc1 = __builtin_amdgcn_mfma_f32_32x32x16_bf16(vf, pB, oacc1, 0, 0, 0);
    }
    __builtin_amdgcn_s_setprio(0);
    // ---- SM1 (overlaps PV0) + PV1 ----
    sm_pack(s1, maskLds + kv0 + 32, hf, dm, lsum, oacc0, oacc1, pA, pB);
    __builtin_amdgcn_s_setprio(1);
    {
      bf16x8 vf;
      vf = *reinterpret_cast<const bf16x8*>(Vs + cl * 128 + ((64 + hf * 16) ^ swz));
      oacc0 = __builtin_amdgcn_mfma_f32_32x32x16_bf16(vf, pA, oacc0, 0, 0, 0);
      vf = *reinterpret_cast<const bf16x8*>(Vs + (32 + cl) * 128 + ((64 + hf * 16) ^ swz));
      oacc1 = __builtin_amdgcn_mfma_f32_32x32x16_bf16(vf, pA, oacc1, 0, 0, 0);
      vf = *reinterpret_cast<const bf16x8*>(Vs + cl * 128 + ((96 + hf * 16) ^ swz));
      oacc0 = __builtin_amdgcn_mfma_f32_32x32x16_bf16(vf, pB, oacc0, 0, 0, 0);
      vf = *reinterpret_cast<const bf16x8*>(Vs + (32 + cl) * 128 + ((96 + hf * 16) ^ swz));
      oacc1 = __builtin_amdgcn_mfma_f32_32x32x16_bf16(vf, pB, oacc1, 0, 0, 0);
    }
    __builtin_amdgcn_s_setprio(0);
    cur ^= 1;
  }

  // ---- epilogue: O[q][d] = oacc / lsum; d = dsub*32 + (reg&3) + 8*(reg>>2) + 4*hf ----
  const float rinv = 1.0f / lsum;
  float* orow = out + ((size_t)bI * S_ + q0 + cl) * D_ + hI * HD_;
  #pragma unroll
  for (int jj = 0; jj < 4; ++jj) {
    float4 o0 = {oacc0[4*jj] * rinv, oacc0[4*jj+1] * rinv, oacc0[4*jj+2] * rinv, oacc0[4*jj+3] * rinv};
    float4 o1 = {oacc1[4*jj] * rinv, oacc1[4*jj+1] * rinv, oacc1[4*jj+2] * rinv, oacc1[4*jj+3] * rinv};
    *reinterpret_cast<float4*>(orow + 8*jj + 4*hf)      = o0;
    *reinterpret_cast<float4*>(orow + 32 + 8*jj + 4*hf) = o1;
  }
}

extern "C" void kernel_launch(void* const* d_in, const int* in_sizes, int n_in,
                              void* d_out, int out_size, void* d_ws, size_t ws_size,
                              hipStream_t stream) {
  const float* x     = (const float*)d_in[0];
  const float* mask  = (const float*)d_in[1];
  const float* gamma = (const float*)d_in[2];
  const float* beta  = (const float*)d_in[3];
  const float* Wq    = (const float*)d_in[4];
  const float* Wk    = (const float*)d_in[5];
  const float* Wv    = (const float*)d_in[6];
  float* out = (float*)d_out;

  char* ws = (char*)d_ws;
  u16* hbuf = (u16*)ws;                                        // 8 MiB
  u16* wt   = (u16*)(ws + (size_t)M_*D_*2);                    // 6 MiB
  u16* qkv  = (u16*)(ws + (size_t)M_*D_*2 + 3ull*D_*D_*2);     // 24 MiB

  hipLaunchKernelGGL(ln_kernel, dim3(M_), dim3(256), 0, stream, x, gamma, beta, hbuf);
  hipLaunchKernelGGL(wt_kernel, dim3(32, 32, 3), dim3(32, 8), 0, stream, Wq, Wk, Wv, wt);
  hipLaunchKernelGGL(qkv_gemm, dim3(8, 32, 3), dim3(256), 0, stream, hbuf, wt, qkv);
  hipLaunchKernelGGL(attn_kernel, dim3(512), dim3(256), 0, stream, qkv, mask, out);
}